// Round 1
// baseline (197.026 us; speedup 1.0000x reference)
//
#include <hip/hip_runtime.h>
#include <math.h>

// TSMixerH: B=32,C=256,L=336,O=96,K=4,NL=2,DFF=1024
// Round 11:
//  - Per-block k-order ROTATION of the weight streams (phase 1: mod-22,
//    phase 2: and-63). Theory: dispatch-start L2 invalidate makes every
//    mlp dispatch pull ~30 MB cold; all ~32 blocks of an XCD walked the
//    k-stream in lockstep, so L2 miss-dedup capped unique outstanding
//    lines at ~ring-depth x 32KB per XCD -> cold fill ran at ~1.1 TB/s
//    (~26us serialized stream-front). Rotating each block's k start
//    multiplies unique in-flight lines ~22x/64x. Accumulation order is
//    k-insensitive; rot is wave-uniform scalar so ring slots stay static.
//  - Everything else unchanged from round 10 (clean A/B).

typedef unsigned short u16;
typedef unsigned int u32;
typedef unsigned long long u64;

constexpr int B = 32, C = 256, L = 336, O = 96, K = 4, NL = 2, DFF = 1024;
constexpr int TM = 32;
constexpr int NTILES = (B * C) / TM;  // 256
constexpr int LP = 352;               // L padded
constexpr int ZBS = 360;              // bf16 z row stride (u16)
constexpr int HS = 1032;              // bf16 H row stride (u16)

constexpr int DT1 = 32;  // phase-1 d-tiles (32-wide)
constexpr int KT1 = 22;  // phase-1 k-steps (16-deep over LP)
constexpr int LT2 = 11;  // phase-2 l-tiles (32-wide)
constexpr int KT2 = 64;  // phase-2 k-steps (16-deep over DFF)
constexpr int NTH = 6;   // head o-tiles (16x16 path)
constexpr int KSH = 11;  // head k-steps (32-deep)

constexpr int TS1 = KT1 * 512;  // 11264 u16 per d-tile
constexpr int TS2 = KT2 * 512;  // 32768 u16 per l-tile
constexpr int THS = KSH * 512;  // 5632 u16 per o-tile

constexpr int W1FRAGS = DT1 * KT1 * 64;  // 45056
constexpr int W2FRAGS = LT2 * KT2 * 64;  // 45056
constexpr int WHFRAGS = NTH * KSH * 64;  // 4224
constexpr int NW1 = W1FRAGS * K * NL;    // 360448
constexpr int NW2 = W2FRAGS * K * NL;    // 360448
constexpr int NPREP = 176 + 256 + 44 + 1;

typedef __bf16 bf16x8 __attribute__((ext_vector_type(8)));
typedef float f32x4 __attribute__((ext_vector_type(4)));
typedef float f32x16 __attribute__((ext_vector_type(16)));

__device__ __forceinline__ u16 f2bf(float f) {
  union { float f; u32 u; } v;
  v.f = f;
  u32 r = v.u + 0x7fffu + ((v.u >> 16) & 1u);  // RNE
  return (u16)(r >> 16);
}
__device__ __forceinline__ float bf2f(u16 h) {
  union { u32 u; float f; } v;
  v.u = ((u32)h) << 16;
  return v.f;
}
__device__ __forceinline__ u32 pack2(float a, float b) {
  return (u32)f2bf(a) | ((u32)f2bf(b) << 16);
}

// ---- merged prep: repacks (blocks 0..475) + tables (block 476) ----
// 32x32x16 A-frag: lane holds A[m=lane&31][k=(lane>>5)*8+j], j=0..7.
//  w1 frag(kl,dt,ks)[lane][j] = W1[kl][l=16ks+(lane>>5)*8+j][d=32dt+(lane&31)]
//  w2 frag(kl,lt,ks)[lane][j] = W2[kl][d=16ks+(lane>>5)*8+j][l=32lt+(lane&31)]
// 16x16x32 A-frag (head, unchanged): lane holds A[m=lane&15][k=(lane>>4)*8+j]
//  wh frag(kk,nt,ks)[lane][j] = Wh[kk][l=32ks+(lane>>4)*8+j][o=16nt+(lane&15)]
// all zero-padded where l>=L.
// meta (ints): [0..255] tiles (k<<16|rstart), [256..511] chlist, [512..] cofs
__global__ __launch_bounds__(256) void prep(const int* __restrict__ assign,
                                            const float* __restrict__ W1,
                                            const float* __restrict__ W2,
                                            const float* __restrict__ Wh,
                                            int* __restrict__ meta,
                                            u16* __restrict__ wbuf) {
  __shared__ u16 sm[32][516];
  const int bid = blockIdx.x;
  const int tid = threadIdx.x;
  const int wid = tid >> 6, lane = tid & 63;
  const int q = lane >> 4, rm = lane & 15;    // 16x16 emit (head)
  const int q2 = lane >> 5, n32 = lane & 31;  // 32x32 emit

  if (bid < 176) {  // ---- W1 ----
    const int dh = bid & 1;
    const int ks32 = (bid >> 1) % 11;
    const int kl = bid / 22;
    // stage: 32 l-rows x 512 d (this half), coalesced float4 reads
    for (int rr = 0; rr < 8; ++rr) {
      const int r = wid * 8 + rr;
      const int l = ks32 * 32 + r;
#pragma unroll
      for (int h = 0; h < 2; ++h) {
        const int c = h * 256 + lane * 4;
        float4 v = make_float4(0.f, 0.f, 0.f, 0.f);
        if (l < L)
          v = *(const float4*)(W1 + ((size_t)kl * L + l) * DFF + dh * 512 + c);
        uint2 p;
        p.x = pack2(v.x, v.y);
        p.y = pack2(v.z, v.w);
        *(uint2*)&sm[r][c] = p;
      }
    }
    __syncthreads();
    // emit: 16 local d-tiles x 2 k16-halves = 32 items
    for (int e = 0; e < 8; ++e) {
      const int item = wid * 8 + e;
      const int dtl = item >> 1, half = item & 1;
      const int rb = 16 * half + q2 * 8;
      const int col = dtl * 32 + n32;
      uint4 o;
      u32 w4[4];
#pragma unroll
      for (int jj = 0; jj < 4; ++jj)
        w4[jj] = (u32)sm[rb + 2 * jj][col] | ((u32)sm[rb + 2 * jj + 1][col] << 16);
      o.x = w4[0]; o.y = w4[1]; o.z = w4[2]; o.w = w4[3];
      const int dt = dh * 16 + dtl;
      const int ks = ks32 * 2 + half;
      *(uint4*)(wbuf + ((size_t)(kl * DT1 + dt) * KT1 + ks) * 512 + lane * 8) = o;
    }
  } else if (bid < 432) {  // ---- W2 ----
    const int b2i = bid - 176;
    const int ks32 = b2i & 31;
    const int kl = b2i >> 5;
    for (int rr = 0; rr < 8; ++rr) {
      const int r = wid * 8 + rr;  // local d
      const float* row = W2 + ((size_t)kl * DFF + ks32 * 32 + r) * L;
      {
        const int c = lane * 4;  // 0..255
        const float4 v = *(const float4*)(row + c);
        uint2 p;
        p.x = pack2(v.x, v.y);
        p.y = pack2(v.z, v.w);
        *(uint2*)&sm[r][c] = p;
      }
      {
        const int c = 256 + lane * 4;  // 256..511; keep c<352, zero c>=336
        if (c < 352) {
          float4 v = make_float4(0.f, 0.f, 0.f, 0.f);
          if (c < L) v = *(const float4*)(row + c);
          uint2 p;
          p.x = pack2(v.x, v.y);
          p.y = pack2(v.z, v.w);
          *(uint2*)&sm[r][c] = p;
        }
      }
    }
    __syncthreads();
    // emit: 11 l-tiles x 2 halves = 22 items
    for (int item = wid; item < 22; item += 4) {
      const int lt = item >> 1, half = item & 1;
      const int rb = 16 * half + q2 * 8;
      const int col = 32 * lt + n32;
      uint4 o;
      u32 w4[4];
#pragma unroll
      for (int jj = 0; jj < 4; ++jj)
        w4[jj] = (u32)sm[rb + 2 * jj][col] | ((u32)sm[rb + 2 * jj + 1][col] << 16);
      o.x = w4[0]; o.y = w4[1]; o.z = w4[2]; o.w = w4[3];
      const int ks = ks32 * 2 + half;
      *(uint4*)(wbuf + (size_t)NW1 * 8 +
                ((size_t)(kl * LT2 + lt) * KT2 + ks) * 512 + lane * 8) = o;
    }
  } else if (bid < 476) {  // ---- Wh (16x16 format, unchanged) ----
    const int b3i = bid - 432;
    const int ks = b3i % 11;
    const int kk = b3i / 11;
    for (int rr = 0; rr < 8; ++rr) {
      const int r = wid * 8 + rr;
      const int l = ks * 32 + r;
      if (lane < 24) {
        const int c = lane * 4;
        float4 v = make_float4(0.f, 0.f, 0.f, 0.f);
        if (l < L) v = *(const float4*)(Wh + ((size_t)kk * L + l) * O + c);
        uint2 p;
        p.x = pack2(v.x, v.y);
        p.y = pack2(v.z, v.w);
        *(uint2*)&sm[r][c] = p;
      }
    }
    __syncthreads();
    for (int nt = wid; nt < NTH; nt += 4) {
      uint4 o;
      u32 w4[4];
#pragma unroll
      for (int jj = 0; jj < 4; ++jj) {
        const u16 a = sm[q * 8 + 2 * jj][nt * 16 + rm];
        const u16 b = sm[q * 8 + 2 * jj + 1][nt * 16 + rm];
        w4[jj] = (u32)a | ((u32)b << 16);
      }
      o.x = w4[0]; o.y = w4[1]; o.z = w4[2]; o.w = w4[3];
      *(uint4*)(wbuf + (size_t)(NW1 + NW2) * 8 +
                ((size_t)(kk * NTH + nt) * KSH + ks) * 512 + lane * 8) = o;
    }
  } else {  // ---- tables ----
    __shared__ int wcnt[4][K];
    __shared__ int pre[4][K];
    __shared__ int cofs[K + 1];
    const int a = assign[tid];
    const u64 below = (1ull << lane) - 1ull;
    int myrank = 0;
#pragma unroll
    for (int k = 0; k < K; ++k) {
      const u64 m = __ballot(a == k);
      if (a == k) myrank = (int)__popcll(m & below);
      if (lane == 0) wcnt[wid][k] = (int)__popcll(m);
    }
    __syncthreads();
    if (tid == 0) {
      int tot[K];
      for (int k = 0; k < K; ++k) {
        int s = 0;
        for (int ww = 0; ww < 4; ++ww) {
          pre[ww][k] = s;
          s += wcnt[ww][k];
        }
        tot[k] = s;
      }
      cofs[0] = 0;
      for (int k = 0; k < K; ++k) cofs[k + 1] = cofs[k] + tot[k];
      for (int k = 0; k <= K; ++k) meta[512 + k] = cofs[k];
    }
    __syncthreads();
    const int pos = cofs[a] + pre[wid][a] + myrank;
    meta[256 + pos] = tid;  // chlist
    int k = 0;
    while (k < K - 1 && tid >= cofs[k + 1]) ++k;
    meta[tid] = (k << 16) | ((tid - cofs[k]) * TM);
  }
}

// ---- main kernel: 16 waves/block, 1 block/CU, 32x32x16 MFMA ----
__global__ __launch_bounds__(1024, 4) void mlp_mfma(
    const float* __restrict__ x, const float* __restrict__ rev_w,
    const float* __restrict__ rev_b, const float* __restrict__ b1,
    const float* __restrict__ b2, const float* __restrict__ bh,
    const int* __restrict__ meta, const u16* __restrict__ wbuf,
    float* __restrict__ out) {
  __shared__ __align__(16) u16 zb[TM][ZBS];  // 23.0 KB
  __shared__ __align__(16) u16 Hsh[TM][HS];  // 66.0 KB
  __shared__ float s_mean[TM], s_std[TM], s_rw[TM], s_rb[TM];
  __shared__ int s_b[TM], s_c[TM];

  const int tid = threadIdx.x;
  const int wid = tid >> 6;  // 0..15
  const int lane = tid & 63;
  const int q = lane >> 4, rm = lane & 15;    // head (16x16)
  const int q2 = lane >> 5, n32 = lane & 31;  // 32x32

  const int swz = (blockIdx.x & 7) * 32 + (blockIdx.x >> 3);
  const int info = meta[swz];
  const int kcl = info >> 16;
  const int rstart = info & 0xffff;
  const int cofs = meta[512 + kcl];
  const int cnt = meta[512 + kcl + 1] - cofs;

  // per-block k-rotation (wave-uniform scalars; slot in [0,32) is the
  // block's position within its XCD under the %8 dispatch round-robin)
  const int slot = blockIdx.x >> 3;
  const int rot1 = (slot * 5) % KT1;      // phase-1 start slice
  const int rot2 = (slot * 7) & (KT2 - 1);  // phase-2 start slice

  // ---- RevIN: 2 rows per wave ----
  for (int i = 0; i < 2; ++i) {
    const int t = wid * 2 + i;
    const int ri = rstart + t;
    const int b = ri / cnt;
    const int c = meta[256 + cofs + (ri % cnt)];
    const float* xrow = x + (size_t)(b * C + c) * L;
    float v[6], s = 0.f, s2 = 0.f;
#pragma unroll
    for (int jj = 0; jj < 6; ++jj) {
      const int j = lane + jj * 64;
      v[jj] = (j < L) ? xrow[j] : 0.f;
      s += v[jj];
      s2 += v[jj] * v[jj];
    }
#pragma unroll
    for (int off = 32; off > 0; off >>= 1) {
      s += __shfl_down(s, off);
      s2 += __shfl_down(s2, off);
    }
    s = __shfl(s, 0);
    s2 = __shfl(s2, 0);
    const float mean = s * (1.f / L);
    const float var = s2 * (1.f / L) - mean * mean;
    const float stdv = sqrtf(var + 1e-5f);
    const float rstd = 1.f / stdv;
    const float rw = rev_w[c], rb_ = rev_b[c];
#pragma unroll
    for (int jj = 0; jj < 6; ++jj) {
      const int j = lane + jj * 64;
      if (j < L) zb[t][j] = f2bf((v[jj] - mean) * rstd * rw + rb_);
    }
    if (lane < LP - L) zb[t][L + lane] = 0;
    if (lane == 0) {
      s_mean[t] = mean;
      s_std[t] = stdv;
      s_rw[t] = rw;
      s_rb[t] = rb_;
      s_b[t] = b;
      s_c[t] = c;
    }
  }

  const u16* w1b = wbuf;
  const u16* w2b = wbuf + (size_t)NW1 * 8;
  const u16* whb = wbuf + (size_t)(NW1 + NW2) * 8;

  // preload layer-0 phase-1 ring (2 d-tiles x depth 4) before barrier
  bf16x8 a1[2][4];
  {
    const u16* b0 = w1b + (size_t)(kcl * NL) * W1FRAGS * 8 +
                    (size_t)(wid * 2) * TS1 + lane * 8;
#pragma unroll
    for (int t = 0; t < 2; ++t)
#pragma unroll
      for (int s = 0; s < 4; ++s) {
        int k0 = rot1 + s;
        if (k0 >= KT1) k0 -= KT1;
        a1[t][s] = *(const bf16x8*)(b0 + (size_t)t * TS1 + k0 * 512);
      }
  }
  __syncthreads();  // zb ready

  // ---- fp32 residual master (D32 layout), waves 0..10 own l-tile wid ----
  f32x16 zm;
#pragma unroll
  for (int i = 0; i < 16; ++i) zm[i] = 0.f;
  if (wid < LT2) {
#pragma unroll
    for (int g = 0; g < 4; ++g) {
      const uint2 zw = *(const uint2*)&zb[n32][32 * wid + 8 * g + 4 * q2];
      zm[4 * g + 0] = bf2f((u16)zw.x);
      zm[4 * g + 1] = bf2f((u16)(zw.x >> 16));
      zm[4 * g + 2] = bf2f((u16)zw.y);
      zm[4 * g + 3] = bf2f((u16)(zw.y >> 16));
    }
  }

  for (int l = 0; l < NL; ++l) {
    const int kl = kcl * NL + l;
    const u16* W1f = w1b + (size_t)kl * W1FRAGS * 8;
    const u16* W2f = w2b + (size_t)kl * W2FRAGS * 8;
    const float* b1p = b1 + kl * DFF;
    const float* b2p = b2 + kl * L;
    const u16* base1 = W1f + (size_t)(wid * 2) * TS1 + lane * 8;

    // -- phase 1: H = relu(z @ W1 + b1); 2 d-tiles/wave, depth-4 ring,
    //    k-order rotated by rot1 (block-unique stream front)
    f32x16 acc[2];
#pragma unroll
    for (int t = 0; t < 2; ++t)
#pragma unroll
      for (int i = 0; i < 16; ++i) acc[t][i] = 0.f;
#pragma unroll
    for (int ks = 0; ks < KT1; ++ks) {
      int kk = ks + rot1;
      if (kk >= KT1) kk -= KT1;
      const bf16x8 zf = *(const bf16x8*)&zb[n32][kk * 16 + q2 * 8];
#pragma unroll
      for (int t = 0; t < 2; ++t)
        acc[t] = __builtin_amdgcn_mfma_f32_32x32x16_bf16(a1[t][ks & 3], zf,
                                                         acc[t], 0, 0, 0);
      if (ks + 4 < KT1) {
        int kn = ks + 4 + rot1;
        if (kn >= KT1) kn -= KT1;
#pragma unroll
        for (int t = 0; t < 2; ++t)
          a1[t][ks & 3] =
              *(const bf16x8*)(base1 + (size_t)t * TS1 + kn * 512);
      }
    }
    // epilogue: bias+relu, write Hsh[sample][d]
#pragma unroll
    for (int t = 0; t < 2; ++t) {
      const int dt = wid * 2 + t;
#pragma unroll
      for (int g = 0; g < 4; ++g) {
        const int db = dt * 32 + 8 * g + 4 * q2;
        const float4 bq = *(const float4*)(b1p + db);
        uint2 hw;
        hw.x = pack2(fmaxf(acc[t][4 * g + 0] + bq.x, 0.f),
                     fmaxf(acc[t][4 * g + 1] + bq.y, 0.f));
        hw.y = pack2(fmaxf(acc[t][4 * g + 2] + bq.z, 0.f),
                     fmaxf(acc[t][4 * g + 3] + bq.w, 0.f));
        *(uint2*)&Hsh[n32][db] = hw;
      }
    }

    // preload phase-2 ring (depth 8, rotated) before the barrier
    bf16x8 a2[8];
    const u16* base2 = W2f + (size_t)wid * TS2 + lane * 8;
    if (wid < LT2) {
#pragma unroll
      for (int s = 0; s < 8; ++s)
        a2[s] = *(const bf16x8*)(base2 + ((s + rot2) & (KT2 - 1)) * 512);
    }
    __syncthreads();  // Hsh ready

    // -- phase 2: zm += H @ W2; 1 l-tile/wave (waves 0..10), depth-8 ring,
    //    k-order rotated by rot2
    if (wid < LT2) {
#pragma unroll
      for (int ks = 0; ks < KT2; ++ks) {
        const int kk = (ks + rot2) & (KT2 - 1);
        const bf16x8 hf = *(const bf16x8*)&Hsh[n32][kk * 16 + q2 * 8];
        zm = __builtin_amdgcn_mfma_f32_32x32x16_bf16(a2[ks & 7], hf, zm, 0, 0, 0);
        if (ks + 8 < KT2)
          a2[ks & 7] =
              *(const bf16x8*)(base2 + ((ks + 8 + rot2) & (KT2 - 1)) * 512);
      }
      // epilogue: zm += b2, refresh bf16 zb
#pragma unroll
      for (int g = 0; g < 4; ++g) {
        const int lc = 32 * wid + 8 * g + 4 * q2;
        if (lc < L) {
          const float4 bq = *(const float4*)(b2p + lc);
          zm[4 * g + 0] += bq.x;
          zm[4 * g + 1] += bq.y;
          zm[4 * g + 2] += bq.z;
          zm[4 * g + 3] += bq.w;
        }
        uint2 zw;
        zw.x = pack2(zm[4 * g + 0], zm[4 * g + 1]);
        zw.y = pack2(zm[4 * g + 2], zm[4 * g + 3]);
        *(uint2*)&zb[n32][lc] = zw;
      }
    }

    // preload next layer's phase-1 ring before the barrier (rotated)
    if (l + 1 < NL) {
      const u16* nb = w1b + (size_t)(kl + 1) * W1FRAGS * 8 +
                      (size_t)(wid * 2) * TS1 + lane * 8;
#pragma unroll
      for (int t = 0; t < 2; ++t)
#pragma unroll
        for (int s = 0; s < 4; ++s) {
          int k0 = rot1 + s;
          if (k0 >= KT1) k0 -= KT1;
          a1[t][s] = *(const bf16x8*)(nb + (size_t)t * TS1 + k0 * 512);
        }
    }
    __syncthreads();  // zb final for this layer
  }

  // ---- head (16x16 path): y = z @ Wh + bh, denorm, scatter out[b][o][c] ----
  if (wid < NTH) {
    const u16* Whf =
        whb + (size_t)kcl * WHFRAGS * 8 + (size_t)wid * THS + lane * 8;
    f32x4 acc0 = {0.f, 0.f, 0.f, 0.f}, acc1 = {0.f, 0.f, 0.f, 0.f};
    for (int ks = 0; ks < KSH; ++ks) {
      const bf16x8 af = *(const bf16x8*)(Whf + ks * 512);
      const bf16x8 zf0 = *(const bf16x8*)&zb[rm][ks * 32 + q * 8];
      const bf16x8 zf1 = *(const bf16x8*)&zb[rm + 16][ks * 32 + q * 8];
      acc0 = __builtin_amdgcn_mfma_f32_16x16x32_bf16(af, zf0, acc0, 0, 0, 0);
      acc1 = __builtin_amdgcn_mfma_f32_16x16x32_bf16(af, zf1, acc1, 0, 0, 0);
    }
    const float4 bq = *(const float4*)(bh + kcl * O + wid * 16 + q * 4);
    const float bqa[4] = {bq.x, bq.y, bq.z, bq.w};
#pragma unroll
    for (int rg = 0; rg < 2; ++rg) {
      const int row = rm + 16 * rg;
      const float mean = s_mean[row], stdv = s_std[row];
      const float rw = s_rw[row], rb_ = s_rb[row];
      const int ob = s_b[row], oc = s_c[row];
      const f32x4 acc = rg ? acc1 : acc0;
#pragma unroll
      for (int gg = 0; gg < 4; ++gg) {
        const int o = wid * 16 + q * 4 + gg;
        const float y = acc[gg] + bqa[gg];
        out[((size_t)ob * O + o) * C + oc] = (y - rb_) / rw * stdv + mean;
      }
    }
  }
}

extern "C" void kernel_launch(void* const* d_in, const int* in_sizes, int n_in,
                              void* d_out, int out_size, void* d_ws,
                              size_t ws_size, hipStream_t stream) {
  const float* x = (const float*)d_in[0];
  const float* rev_w = (const float*)d_in[1];
  const float* rev_b = (const float*)d_in[2];
  const float* W1 = (const float*)d_in[3];
  const float* b1 = (const float*)d_in[4];
  const float* W2 = (const float*)d_in[5];
  const float* b2 = (const float*)d_in[6];
  const float* Wh = (const float*)d_in[7];
  const float* bh = (const float*)d_in[8];
  const int* assign = (const int*)d_in[9];
  float* out = (float*)d_out;

  int* meta = (int*)d_ws;                  // ~2.1 KB
  u16* wbuf = (u16*)((char*)d_ws + 4096);  // 11.8 MB bf16 fragments

  prep<<<NPREP, 256, 0, stream>>>(assign, W1, W2, Wh, meta, wbuf);
  mlp_mfma<<<NTILES, 1024, 0, stream>>>(x, rev_w, rev_b, b1, b2, bh, meta,
                                        wbuf, out);
}

// Round 2
// 161.246 us; speedup vs baseline: 1.2219x; 1.2219x over previous
//
#include <hip/hip_runtime.h>
#include <math.h>

// TSMixerH: B=32,C=256,L=336,O=96,K=4,NL=2,DFF=1024
// Round 12:
//  - REVERT r11 k-rotation (FETCH 30.7->116.7 MB, WRITE 30.6->149.4 MB,
//    55->107us: desync destroyed cross-block L2 dedup of the shared
//    weight stream and out-line coalescing. Lockstep consumption is
//    load-bearing; restored exactly).
//  - Keep the diagnosis: cold fill ran at 1.15 TB/s because lockstep
//    dedup caps unique outstanding bytes/XCD at ~one CU's ring set
//    (~88KB / 900ns ~ 1 TB/s chip). Fix the SUPPLY side instead:
//    slot-staggered fire-and-forget L2 PREFETCH. Each block touches a
//    distinct 1/32 chunk of the upcoming layer's weight stream
//    (slot = blockIdx>>3), so the 32 blocks of a cluster collectively
//    keep ~MBs in flight while consuming loads stay lockstep (L2-warm).
//    Layer-0 stream: prefetched at kernel start (overlaps RevIN).
//    Layer-1 stream: prefetched by the 5 idle waves during phase 2.
//    Wh: prefetched by idle waves during the last phase 2.
//    Loads kept alive via asm volatile (rule #17), results discarded.

typedef unsigned short u16;
typedef unsigned int u32;
typedef unsigned long long u64;

constexpr int B = 32, C = 256, L = 336, O = 96, K = 4, NL = 2, DFF = 1024;
constexpr int TM = 32;
constexpr int NTILES = (B * C) / TM;  // 256
constexpr int LP = 352;               // L padded
constexpr int ZBS = 360;              // bf16 z row stride (u16)
constexpr int HS = 1032;              // bf16 H row stride (u16)

constexpr int DT1 = 32;  // phase-1 d-tiles (32-wide)
constexpr int KT1 = 22;  // phase-1 k-steps (16-deep over LP)
constexpr int LT2 = 11;  // phase-2 l-tiles (32-wide)
constexpr int KT2 = 64;  // phase-2 k-steps (16-deep over DFF)
constexpr int NTH = 6;   // head o-tiles (16x16 path)
constexpr int KSH = 11;  // head k-steps (32-deep)

constexpr int TS1 = KT1 * 512;  // 11264 u16 per d-tile
constexpr int TS2 = KT2 * 512;  // 32768 u16 per l-tile
constexpr int THS = KSH * 512;  // 5632 u16 per o-tile

constexpr int W1FRAGS = DT1 * KT1 * 64;  // 45056
constexpr int W2FRAGS = LT2 * KT2 * 64;  // 45056
constexpr int WHFRAGS = NTH * KSH * 64;  // 4224
constexpr int NW1 = W1FRAGS * K * NL;    // 360448
constexpr int NW2 = W2FRAGS * K * NL;    // 360448
constexpr int NPREP = 176 + 256 + 44 + 1;

typedef __bf16 bf16x8 __attribute__((ext_vector_type(8)));
typedef float f32x4 __attribute__((ext_vector_type(4)));
typedef float f32x16 __attribute__((ext_vector_type(16)));

__device__ __forceinline__ u16 f2bf(float f) {
  union { float f; u32 u; } v;
  v.f = f;
  u32 r = v.u + 0x7fffu + ((v.u >> 16) & 1u);  // RNE
  return (u16)(r >> 16);
}
__device__ __forceinline__ float bf2f(u16 h) {
  union { u32 u; float f; } v;
  v.u = ((u32)h) << 16;
  return v.f;
}
__device__ __forceinline__ u32 pack2(float a, float b) {
  return (u32)f2bf(a) | ((u32)f2bf(b) << 16);
}

// fire-and-forget L2 prefetch: dwordx4 loads, results kept alive but unused
__device__ __forceinline__ void pf(const u16* region, u32 rbytes, u32 off0,
                                   u32 step, int rounds) {
  u32 k0 = 0, k1 = 0, k2 = 0, k3 = 0;
  for (int r = 0; r < rounds; ++r) {
    const u32 a = off0 + (u32)r * step;
    if (a < rbytes) {
      const uint4 v = *(const uint4*)((const char*)region + a);
      k0 ^= v.x; k1 ^= v.y; k2 ^= v.z; k3 ^= v.w;
    }
  }
  asm volatile("" ::"v"(k0), "v"(k1), "v"(k2), "v"(k3));
}

// ---- merged prep: repacks (blocks 0..475) + tables (block 476) ----
// 32x32x16 A-frag: lane holds A[m=lane&31][k=(lane>>5)*8+j], j=0..7.
//  w1 frag(kl,dt,ks)[lane][j] = W1[kl][l=16ks+(lane>>5)*8+j][d=32dt+(lane&31)]
//  w2 frag(kl,lt,ks)[lane][j] = W2[kl][d=16ks+(lane>>5)*8+j][l=32lt+(lane&31)]
// 16x16x32 A-frag (head, unchanged): lane holds A[m=lane&15][k=(lane>>4)*8+j]
//  wh frag(kk,nt,ks)[lane][j] = Wh[kk][l=32ks+(lane>>4)*8+j][o=16nt+(lane&15)]
// all zero-padded where l>=L.
// meta (ints): [0..255] tiles (k<<16|rstart), [256..511] chlist, [512..] cofs
__global__ __launch_bounds__(256) void prep(const int* __restrict__ assign,
                                            const float* __restrict__ W1,
                                            const float* __restrict__ W2,
                                            const float* __restrict__ Wh,
                                            int* __restrict__ meta,
                                            u16* __restrict__ wbuf) {
  __shared__ u16 sm[32][516];
  const int bid = blockIdx.x;
  const int tid = threadIdx.x;
  const int wid = tid >> 6, lane = tid & 63;
  const int q = lane >> 4, rm = lane & 15;    // 16x16 emit (head)
  const int q2 = lane >> 5, n32 = lane & 31;  // 32x32 emit

  if (bid < 176) {  // ---- W1 ----
    const int dh = bid & 1;
    const int ks32 = (bid >> 1) % 11;
    const int kl = bid / 22;
    // stage: 32 l-rows x 512 d (this half), coalesced float4 reads
    for (int rr = 0; rr < 8; ++rr) {
      const int r = wid * 8 + rr;
      const int l = ks32 * 32 + r;
#pragma unroll
      for (int h = 0; h < 2; ++h) {
        const int c = h * 256 + lane * 4;
        float4 v = make_float4(0.f, 0.f, 0.f, 0.f);
        if (l < L)
          v = *(const float4*)(W1 + ((size_t)kl * L + l) * DFF + dh * 512 + c);
        uint2 p;
        p.x = pack2(v.x, v.y);
        p.y = pack2(v.z, v.w);
        *(uint2*)&sm[r][c] = p;
      }
    }
    __syncthreads();
    // emit: 16 local d-tiles x 2 k16-halves = 32 items
    for (int e = 0; e < 8; ++e) {
      const int item = wid * 8 + e;
      const int dtl = item >> 1, half = item & 1;
      const int rb = 16 * half + q2 * 8;
      const int col = dtl * 32 + n32;
      uint4 o;
      u32 w4[4];
#pragma unroll
      for (int jj = 0; jj < 4; ++jj)
        w4[jj] = (u32)sm[rb + 2 * jj][col] | ((u32)sm[rb + 2 * jj + 1][col] << 16);
      o.x = w4[0]; o.y = w4[1]; o.z = w4[2]; o.w = w4[3];
      const int dt = dh * 16 + dtl;
      const int ks = ks32 * 2 + half;
      *(uint4*)(wbuf + ((size_t)(kl * DT1 + dt) * KT1 + ks) * 512 + lane * 8) = o;
    }
  } else if (bid < 432) {  // ---- W2 ----
    const int b2i = bid - 176;
    const int ks32 = b2i & 31;
    const int kl = b2i >> 5;
    for (int rr = 0; rr < 8; ++rr) {
      const int r = wid * 8 + rr;  // local d
      const float* row = W2 + ((size_t)kl * DFF + ks32 * 32 + r) * L;
      {
        const int c = lane * 4;  // 0..255
        const float4 v = *(const float4*)(row + c);
        uint2 p;
        p.x = pack2(v.x, v.y);
        p.y = pack2(v.z, v.w);
        *(uint2*)&sm[r][c] = p;
      }
      {
        const int c = 256 + lane * 4;  // 256..511; keep c<352, zero c>=336
        if (c < 352) {
          float4 v = make_float4(0.f, 0.f, 0.f, 0.f);
          if (c < L) v = *(const float4*)(row + c);
          uint2 p;
          p.x = pack2(v.x, v.y);
          p.y = pack2(v.z, v.w);
          *(uint2*)&sm[r][c] = p;
        }
      }
    }
    __syncthreads();
    // emit: 11 l-tiles x 2 halves = 22 items
    for (int item = wid; item < 22; item += 4) {
      const int lt = item >> 1, half = item & 1;
      const int rb = 16 * half + q2 * 8;
      const int col = 32 * lt + n32;
      uint4 o;
      u32 w4[4];
#pragma unroll
      for (int jj = 0; jj < 4; ++jj)
        w4[jj] = (u32)sm[rb + 2 * jj][col] | ((u32)sm[rb + 2 * jj + 1][col] << 16);
      o.x = w4[0]; o.y = w4[1]; o.z = w4[2]; o.w = w4[3];
      const int ks = ks32 * 2 + half;
      *(uint4*)(wbuf + (size_t)NW1 * 8 +
                ((size_t)(kl * LT2 + lt) * KT2 + ks) * 512 + lane * 8) = o;
    }
  } else if (bid < 476) {  // ---- Wh (16x16 format, unchanged) ----
    const int b3i = bid - 432;
    const int ks = b3i % 11;
    const int kk = b3i / 11;
    for (int rr = 0; rr < 8; ++rr) {
      const int r = wid * 8 + rr;
      const int l = ks * 32 + r;
      if (lane < 24) {
        const int c = lane * 4;
        float4 v = make_float4(0.f, 0.f, 0.f, 0.f);
        if (l < L) v = *(const float4*)(Wh + ((size_t)kk * L + l) * O + c);
        uint2 p;
        p.x = pack2(v.x, v.y);
        p.y = pack2(v.z, v.w);
        *(uint2*)&sm[r][c] = p;
      }
    }
    __syncthreads();
    for (int nt = wid; nt < NTH; nt += 4) {
      uint4 o;
      u32 w4[4];
#pragma unroll
      for (int jj = 0; jj < 4; ++jj) {
        const u16 a = sm[q * 8 + 2 * jj][nt * 16 + rm];
        const u16 b = sm[q * 8 + 2 * jj + 1][nt * 16 + rm];
        w4[jj] = (u32)a | ((u32)b << 16);
      }
      o.x = w4[0]; o.y = w4[1]; o.z = w4[2]; o.w = w4[3];
      *(uint4*)(wbuf + (size_t)(NW1 + NW2) * 8 +
                ((size_t)(kk * NTH + nt) * KSH + ks) * 512 + lane * 8) = o;
    }
  } else {  // ---- tables ----
    __shared__ int wcnt[4][K];
    __shared__ int pre[4][K];
    __shared__ int cofs[K + 1];
    const int a = assign[tid];
    const u64 below = (1ull << lane) - 1ull;
    int myrank = 0;
#pragma unroll
    for (int k = 0; k < K; ++k) {
      const u64 m = __ballot(a == k);
      if (a == k) myrank = (int)__popcll(m & below);
      if (lane == 0) wcnt[wid][k] = (int)__popcll(m);
    }
    __syncthreads();
    if (tid == 0) {
      int tot[K];
      for (int k = 0; k < K; ++k) {
        int s = 0;
        for (int ww = 0; ww < 4; ++ww) {
          pre[ww][k] = s;
          s += wcnt[ww][k];
        }
        tot[k] = s;
      }
      cofs[0] = 0;
      for (int k = 0; k < K; ++k) cofs[k + 1] = cofs[k] + tot[k];
      for (int k = 0; k <= K; ++k) meta[512 + k] = cofs[k];
    }
    __syncthreads();
    const int pos = cofs[a] + pre[wid][a] + myrank;
    meta[256 + pos] = tid;  // chlist
    int k = 0;
    while (k < K - 1 && tid >= cofs[k + 1]) ++k;
    meta[tid] = (k << 16) | ((tid - cofs[k]) * TM);
  }
}

// ---- main kernel: 16 waves/block, 1 block/CU, 32x32x16 MFMA ----
__global__ __launch_bounds__(1024, 4) void mlp_mfma(
    const float* __restrict__ x, const float* __restrict__ rev_w,
    const float* __restrict__ rev_b, const float* __restrict__ b1,
    const float* __restrict__ b2, const float* __restrict__ bh,
    const int* __restrict__ meta, const u16* __restrict__ wbuf,
    float* __restrict__ out) {
  __shared__ __align__(16) u16 zb[TM][ZBS];  // 23.0 KB
  __shared__ __align__(16) u16 Hsh[TM][HS];  // 66.0 KB
  __shared__ float s_mean[TM], s_std[TM], s_rw[TM], s_rb[TM];
  __shared__ int s_b[TM], s_c[TM];

  const int tid = threadIdx.x;
  const int wid = tid >> 6;  // 0..15
  const int lane = tid & 63;
  const int q = lane >> 4, rm = lane & 15;    // head (16x16)
  const int q2 = lane >> 5, n32 = lane & 31;  // 32x32

  const int swz = (blockIdx.x & 7) * 32 + (blockIdx.x >> 3);
  const int info = meta[swz];
  const int kcl = info >> 16;
  const int rstart = info & 0xffff;
  const int cofs = meta[512 + kcl];
  const int cnt = meta[512 + kcl + 1] - cofs;

  const u16* w1b = wbuf;
  const u16* w2b = wbuf + (size_t)NW1 * 8;
  const u16* whb = wbuf + (size_t)(NW1 + NW2) * 8;

  // slot in [0,32): block's index within its cluster group -> staggered
  // prefetch chunks so the group collectively covers the whole stream.
  const int slot = blockIdx.x >> 3;
  constexpr u32 SH = 22528;  // per-block share of one 720896-B layer array

  // ---- staggered L2 prefetch of layer-0 weight stream (all 16 waves) ----
  {
    const u16* W1f0 = w1b + (size_t)(kcl * NL) * W1FRAGS * 8;
    const u16* W2f0 = w2b + (size_t)(kcl * NL) * W2FRAGS * 8;
    const u32 off0 = (u32)slot * SH + (u32)wid * 1024 + (u32)lane * 16;
    pf(W1f0, W1FRAGS * 16, off0, 16384, 2);
    pf(W2f0, W2FRAGS * 16, off0, 16384, 2);
  }

  // ---- RevIN: 2 rows per wave ----
  for (int i = 0; i < 2; ++i) {
    const int t = wid * 2 + i;
    const int ri = rstart + t;
    const int b = ri / cnt;
    const int c = meta[256 + cofs + (ri % cnt)];
    const float* xrow = x + (size_t)(b * C + c) * L;
    float v[6], s = 0.f, s2 = 0.f;
#pragma unroll
    for (int jj = 0; jj < 6; ++jj) {
      const int j = lane + jj * 64;
      v[jj] = (j < L) ? xrow[j] : 0.f;
      s += v[jj];
      s2 += v[jj] * v[jj];
    }
#pragma unroll
    for (int off = 32; off > 0; off >>= 1) {
      s += __shfl_down(s, off);
      s2 += __shfl_down(s2, off);
    }
    s = __shfl(s, 0);
    s2 = __shfl(s2, 0);
    const float mean = s * (1.f / L);
    const float var = s2 * (1.f / L) - mean * mean;
    const float stdv = sqrtf(var + 1e-5f);
    const float rstd = 1.f / stdv;
    const float rw = rev_w[c], rb_ = rev_b[c];
#pragma unroll
    for (int jj = 0; jj < 6; ++jj) {
      const int j = lane + jj * 64;
      if (j < L) zb[t][j] = f2bf((v[jj] - mean) * rstd * rw + rb_);
    }
    if (lane < LP - L) zb[t][L + lane] = 0;
    if (lane == 0) {
      s_mean[t] = mean;
      s_std[t] = stdv;
      s_rw[t] = rw;
      s_rb[t] = rb_;
      s_b[t] = b;
      s_c[t] = c;
    }
  }

  // preload layer-0 phase-1 ring (2 d-tiles x depth 4) before barrier
  bf16x8 a1[2][4];
  {
    const u16* b0 = w1b + (size_t)(kcl * NL) * W1FRAGS * 8 +
                    (size_t)(wid * 2) * TS1 + lane * 8;
#pragma unroll
    for (int t = 0; t < 2; ++t)
#pragma unroll
      for (int s = 0; s < 4; ++s)
        a1[t][s] = *(const bf16x8*)(b0 + (size_t)t * TS1 + s * 512);
  }
  __syncthreads();  // zb ready

  // ---- fp32 residual master (D32 layout), waves 0..10 own l-tile wid ----
  f32x16 zm;
#pragma unroll
  for (int i = 0; i < 16; ++i) zm[i] = 0.f;
  if (wid < LT2) {
#pragma unroll
    for (int g = 0; g < 4; ++g) {
      const uint2 zw = *(const uint2*)&zb[n32][32 * wid + 8 * g + 4 * q2];
      zm[4 * g + 0] = bf2f((u16)zw.x);
      zm[4 * g + 1] = bf2f((u16)(zw.x >> 16));
      zm[4 * g + 2] = bf2f((u16)zw.y);
      zm[4 * g + 3] = bf2f((u16)(zw.y >> 16));
    }
  }

  for (int l = 0; l < NL; ++l) {
    const int kl = kcl * NL + l;
    const u16* W1f = w1b + (size_t)kl * W1FRAGS * 8;
    const u16* W2f = w2b + (size_t)kl * W2FRAGS * 8;
    const float* b1p = b1 + kl * DFF;
    const float* b2p = b2 + kl * L;
    const u16* base1 = W1f + (size_t)(wid * 2) * TS1 + lane * 8;

    // -- phase 1: H = relu(z @ W1 + b1); 2 d-tiles/wave, depth-4 ring
    f32x16 acc[2];
#pragma unroll
    for (int t = 0; t < 2; ++t)
#pragma unroll
      for (int i = 0; i < 16; ++i) acc[t][i] = 0.f;
#pragma unroll
    for (int ks = 0; ks < KT1; ++ks) {
      const bf16x8 zf = *(const bf16x8*)&zb[n32][ks * 16 + q2 * 8];
#pragma unroll
      for (int t = 0; t < 2; ++t)
        acc[t] = __builtin_amdgcn_mfma_f32_32x32x16_bf16(a1[t][ks & 3], zf,
                                                         acc[t], 0, 0, 0);
      if (ks + 4 < KT1) {
#pragma unroll
        for (int t = 0; t < 2; ++t)
          a1[t][ks & 3] =
              *(const bf16x8*)(base1 + (size_t)t * TS1 + (ks + 4) * 512);
      }
    }
    // epilogue: bias+relu, write Hsh[sample][d]
#pragma unroll
    for (int t = 0; t < 2; ++t) {
      const int dt = wid * 2 + t;
#pragma unroll
      for (int g = 0; g < 4; ++g) {
        const int db = dt * 32 + 8 * g + 4 * q2;
        const float4 bq = *(const float4*)(b1p + db);
        uint2 hw;
        hw.x = pack2(fmaxf(acc[t][4 * g + 0] + bq.x, 0.f),
                     fmaxf(acc[t][4 * g + 1] + bq.y, 0.f));
        hw.y = pack2(fmaxf(acc[t][4 * g + 2] + bq.z, 0.f),
                     fmaxf(acc[t][4 * g + 3] + bq.w, 0.f));
        *(uint2*)&Hsh[n32][db] = hw;
      }
    }

    // preload phase-2 ring (depth 8) before the barrier (global-only)
    bf16x8 a2[8];
    const u16* base2 = W2f + (size_t)wid * TS2 + lane * 8;
    if (wid < LT2) {
#pragma unroll
      for (int s = 0; s < 8; ++s)
        a2[s] = *(const bf16x8*)(base2 + s * 512);
    }
    __syncthreads();  // Hsh ready

    // -- phase 2: zm += H @ W2; 1 l-tile/wave (waves 0..10), depth-8 ring
    if (wid < LT2) {
#pragma unroll
      for (int ks = 0; ks < KT2; ++ks) {
        const bf16x8 hf = *(const bf16x8*)&Hsh[n32][ks * 16 + q2 * 8];
        zm = __builtin_amdgcn_mfma_f32_32x32x16_bf16(a2[ks & 7], hf, zm, 0, 0, 0);
        if (ks + 8 < KT2)
          a2[ks & 7] = *(const bf16x8*)(base2 + (ks + 8) * 512);
      }
      // epilogue: zm += b2, refresh bf16 zb
#pragma unroll
      for (int g = 0; g < 4; ++g) {
        const int lc = 32 * wid + 8 * g + 4 * q2;
        if (lc < L) {
          const float4 bq = *(const float4*)(b2p + lc);
          zm[4 * g + 0] += bq.x;
          zm[4 * g + 1] += bq.y;
          zm[4 * g + 2] += bq.z;
          zm[4 * g + 3] += bq.w;
        }
        uint2 zw;
        zw.x = pack2(zm[4 * g + 0], zm[4 * g + 1]);
        zw.y = pack2(zm[4 * g + 2], zm[4 * g + 3]);
        *(uint2*)&zb[n32][lc] = zw;
      }
    } else {
      // idle waves (wid 11..15): staggered L2 prefetch of the NEXT stage
      const u32 offi =
          (u32)slot * SH + (u32)(wid - LT2) * 1024 + (u32)lane * 16;
      if (l + 1 < NL) {
        const u16* nW1 = w1b + (size_t)(kl + 1) * W1FRAGS * 8;
        const u16* nW2 = w2b + (size_t)(kl + 1) * W2FRAGS * 8;
        pf(nW1, W1FRAGS * 16, offi, 5120, 5);
        pf(nW2, W2FRAGS * 16, offi, 5120, 5);
      } else {
        const u16* Whr = whb + (size_t)kcl * WHFRAGS * 8;
        const u32 offw =
            (u32)slot * 2112 + (u32)(wid - LT2) * 1024 + (u32)lane * 16;
        pf(Whr, WHFRAGS * 16, offw, 5120, 1);
      }
    }

    // preload next layer's phase-1 ring before the barrier (global-only)
    if (l + 1 < NL) {
      const u16* nb = w1b + (size_t)(kl + 1) * W1FRAGS * 8 +
                      (size_t)(wid * 2) * TS1 + lane * 8;
#pragma unroll
      for (int t = 0; t < 2; ++t)
#pragma unroll
        for (int s = 0; s < 4; ++s)
          a1[t][s] = *(const bf16x8*)(nb + (size_t)t * TS1 + s * 512);
    }
    __syncthreads();  // zb final for this layer
  }

  // ---- head (16x16 path): y = z @ Wh + bh, denorm, scatter out[b][o][c] ----
  if (wid < NTH) {
    const u16* Whf =
        whb + (size_t)kcl * WHFRAGS * 8 + (size_t)wid * THS + lane * 8;
    f32x4 acc0 = {0.f, 0.f, 0.f, 0.f}, acc1 = {0.f, 0.f, 0.f, 0.f};
    for (int ks = 0; ks < KSH; ++ks) {
      const bf16x8 af = *(const bf16x8*)(Whf + ks * 512);
      const bf16x8 zf0 = *(const bf16x8*)&zb[rm][ks * 32 + q * 8];
      const bf16x8 zf1 = *(const bf16x8*)&zb[rm + 16][ks * 32 + q * 8];
      acc0 = __builtin_amdgcn_mfma_f32_16x16x32_bf16(af, zf0, acc0, 0, 0, 0);
      acc1 = __builtin_amdgcn_mfma_f32_16x16x32_bf16(af, zf1, acc1, 0, 0, 0);
    }
    const float4 bq = *(const float4*)(bh + kcl * O + wid * 16 + q * 4);
    const float bqa[4] = {bq.x, bq.y, bq.z, bq.w};
#pragma unroll
    for (int rg = 0; rg < 2; ++rg) {
      const int row = rm + 16 * rg;
      const float mean = s_mean[row], stdv = s_std[row];
      const float rw = s_rw[row], rb_ = s_rb[row];
      const int ob = s_b[row], oc = s_c[row];
      const f32x4 acc = rg ? acc1 : acc0;
#pragma unroll
      for (int gg = 0; gg < 4; ++gg) {
        const int o = wid * 16 + q * 4 + gg;
        const float y = acc[gg] + bqa[gg];
        out[((size_t)ob * O + o) * C + oc] = (y - rb_) / rw * stdv + mean;
      }
    }
  }
}

extern "C" void kernel_launch(void* const* d_in, const int* in_sizes, int n_in,
                              void* d_out, int out_size, void* d_ws,
                              size_t ws_size, hipStream_t stream) {
  const float* x = (const float*)d_in[0];
  const float* rev_w = (const float*)d_in[1];
  const float* rev_b = (const float*)d_in[2];
  const float* W1 = (const float*)d_in[3];
  const float* b1 = (const float*)d_in[4];
  const float* W2 = (const float*)d_in[5];
  const float* b2 = (const float*)d_in[6];
  const float* Wh = (const float*)d_in[7];
  const float* bh = (const float*)d_in[8];
  const int* assign = (const int*)d_in[9];
  float* out = (float*)d_out;

  int* meta = (int*)d_ws;                  // ~2.1 KB
  u16* wbuf = (u16*)((char*)d_ws + 4096);  // 11.8 MB bf16 fragments

  prep<<<NPREP, 256, 0, stream>>>(assign, W1, W2, Wh, meta, wbuf);
  mlp_mfma<<<NTILES, 1024, 0, stream>>>(x, rev_w, rev_b, b1, b2, bh, meta,
                                        wbuf, out);
}

// Round 4
// 144.788 us; speedup vs baseline: 1.3608x; 1.1137x over previous
//
#include <hip/hip_runtime.h>
#include <math.h>

// TSMixerH: B=32,C=256,L=336,O=96,K=4,NL=2,DFF=1024
// Round 14:
//  - r13 FAILED (NaN): y staging buffer carved from d_ws beyond wbuf
//    pushed workspace use 11.61->14.76 MB; y likely landed out of
//    bounds (ws_size insufficient) -> poison reads. Logic itself is
//    correct (chlist/ipos inverse verified).
//  - FIX: y moved to a module-static __device__ array g_y (3.15 MB,
//    allocated at module load; no hipMalloc, graph-capture safe).
//    Workspace footprint back to the proven 11.61 MB.
//  - Theory unchanged (r11/r12 evidence): out[b][o][c] 64B lines are
//    co-written by all 4 clusters = different XCDs -> partial-line
//    ping-pong = 10x write amplification at rest. Hot kernel now writes
//    cluster-packed y[b][o][p] (full-line, single-writer, denorm still
//    fused); tiny scatter_out permutes y->out fully coalesced.

typedef unsigned short u16;
typedef unsigned int u32;
typedef unsigned long long u64;

constexpr int B = 32, C = 256, L = 336, O = 96, K = 4, NL = 2, DFF = 1024;
constexpr int TM = 32;
constexpr int NTILES = (B * C) / TM;  // 256
constexpr int LP = 352;               // L padded
constexpr int ZBS = 360;              // bf16 z row stride (u16)
constexpr int HS = 1032;              // bf16 H row stride (u16)

constexpr int DT1 = 32;  // phase-1 d-tiles (32-wide)
constexpr int KT1 = 22;  // phase-1 k-steps (16-deep over LP)
constexpr int LT2 = 11;  // phase-2 l-tiles (32-wide)
constexpr int KT2 = 64;  // phase-2 k-steps (16-deep over DFF)
constexpr int NTH = 6;   // head o-tiles (16x16 path)
constexpr int KSH = 11;  // head k-steps (32-deep)

constexpr int TS1 = KT1 * 512;  // 11264 u16 per d-tile
constexpr int TS2 = KT2 * 512;  // 32768 u16 per l-tile
constexpr int THS = KSH * 512;  // 5632 u16 per o-tile

constexpr int W1FRAGS = DT1 * KT1 * 64;  // 45056
constexpr int W2FRAGS = LT2 * KT2 * 64;  // 45056
constexpr int WHFRAGS = NTH * KSH * 64;  // 4224
constexpr int NW1 = W1FRAGS * K * NL;    // 360448
constexpr int NW2 = W2FRAGS * K * NL;    // 360448
constexpr int NPREP = 176 + 256 + 44 + 1;

typedef __bf16 bf16x8 __attribute__((ext_vector_type(8)));
typedef float f32x4 __attribute__((ext_vector_type(4)));
typedef float f32x16 __attribute__((ext_vector_type(16)));

// packed-channel staging for out (module-static: NOT in workspace)
__device__ float g_y[(size_t)B * O * C];

__device__ __forceinline__ u16 f2bf(float f) {
  union { float f; u32 u; } v;
  v.f = f;
  u32 r = v.u + 0x7fffu + ((v.u >> 16) & 1u);  // RNE
  return (u16)(r >> 16);
}
__device__ __forceinline__ float bf2f(u16 h) {
  union { u32 u; float f; } v;
  v.u = ((u32)h) << 16;
  return v.f;
}
__device__ __forceinline__ u32 pack2(float a, float b) {
  return (u32)f2bf(a) | ((u32)f2bf(b) << 16);
}

// ---- merged prep: repacks (blocks 0..475) + tables (block 476) ----
// 32x32x16 A-frag: lane holds A[m=lane&31][k=(lane>>5)*8+j], j=0..7.
//  w1 frag(kl,dt,ks)[lane][j] = W1[kl][l=16ks+(lane>>5)*8+j][d=32dt+(lane&31)]
//  w2 frag(kl,lt,ks)[lane][j] = W2[kl][d=16ks+(lane>>5)*8+j][l=32lt+(lane&31)]
// 16x16x32 A-frag (head, unchanged): lane holds A[m=lane&15][k=(lane>>4)*8+j]
//  wh frag(kk,nt,ks)[lane][j] = Wh[kk][l=32ks+(lane>>4)*8+j][o=16nt+(lane&15)]
// all zero-padded where l>=L.
// meta (ints): [0..255] tiles (k<<16|rstart), [256..511] chlist,
//              [512..516] cofs, [520..775] ipos (inverse chlist)
__global__ __launch_bounds__(256) void prep(const int* __restrict__ assign,
                                            const float* __restrict__ W1,
                                            const float* __restrict__ W2,
                                            const float* __restrict__ Wh,
                                            int* __restrict__ meta,
                                            u16* __restrict__ wbuf) {
  __shared__ u16 sm[32][516];
  const int bid = blockIdx.x;
  const int tid = threadIdx.x;
  const int wid = tid >> 6, lane = tid & 63;
  const int q = lane >> 4, rm = lane & 15;    // 16x16 emit (head)
  const int q2 = lane >> 5, n32 = lane & 31;  // 32x32 emit

  if (bid < 176) {  // ---- W1 ----
    const int dh = bid & 1;
    const int ks32 = (bid >> 1) % 11;
    const int kl = bid / 22;
    // stage: 32 l-rows x 512 d (this half), coalesced float4 reads
    for (int rr = 0; rr < 8; ++rr) {
      const int r = wid * 8 + rr;
      const int l = ks32 * 32 + r;
#pragma unroll
      for (int h = 0; h < 2; ++h) {
        const int c = h * 256 + lane * 4;
        float4 v = make_float4(0.f, 0.f, 0.f, 0.f);
        if (l < L)
          v = *(const float4*)(W1 + ((size_t)kl * L + l) * DFF + dh * 512 + c);
        uint2 p;
        p.x = pack2(v.x, v.y);
        p.y = pack2(v.z, v.w);
        *(uint2*)&sm[r][c] = p;
      }
    }
    __syncthreads();
    // emit: 16 local d-tiles x 2 k16-halves = 32 items
    for (int e = 0; e < 8; ++e) {
      const int item = wid * 8 + e;
      const int dtl = item >> 1, half = item & 1;
      const int rb = 16 * half + q2 * 8;
      const int col = dtl * 32 + n32;
      uint4 o;
      u32 w4[4];
#pragma unroll
      for (int jj = 0; jj < 4; ++jj)
        w4[jj] = (u32)sm[rb + 2 * jj][col] | ((u32)sm[rb + 2 * jj + 1][col] << 16);
      o.x = w4[0]; o.y = w4[1]; o.z = w4[2]; o.w = w4[3];
      const int dt = dh * 16 + dtl;
      const int ks = ks32 * 2 + half;
      *(uint4*)(wbuf + ((size_t)(kl * DT1 + dt) * KT1 + ks) * 512 + lane * 8) = o;
    }
  } else if (bid < 432) {  // ---- W2 ----
    const int b2i = bid - 176;
    const int ks32 = b2i & 31;
    const int kl = b2i >> 5;
    for (int rr = 0; rr < 8; ++rr) {
      const int r = wid * 8 + rr;  // local d
      const float* row = W2 + ((size_t)kl * DFF + ks32 * 32 + r) * L;
      {
        const int c = lane * 4;  // 0..255
        const float4 v = *(const float4*)(row + c);
        uint2 p;
        p.x = pack2(v.x, v.y);
        p.y = pack2(v.z, v.w);
        *(uint2*)&sm[r][c] = p;
      }
      {
        const int c = 256 + lane * 4;  // 256..511; keep c<352, zero c>=336
        if (c < 352) {
          float4 v = make_float4(0.f, 0.f, 0.f, 0.f);
          if (c < L) v = *(const float4*)(row + c);
          uint2 p;
          p.x = pack2(v.x, v.y);
          p.y = pack2(v.z, v.w);
          *(uint2*)&sm[r][c] = p;
        }
      }
    }
    __syncthreads();
    // emit: 11 l-tiles x 2 halves = 22 items
    for (int item = wid; item < 22; item += 4) {
      const int lt = item >> 1, half = item & 1;
      const int rb = 16 * half + q2 * 8;
      const int col = 32 * lt + n32;
      uint4 o;
      u32 w4[4];
#pragma unroll
      for (int jj = 0; jj < 4; ++jj)
        w4[jj] = (u32)sm[rb + 2 * jj][col] | ((u32)sm[rb + 2 * jj + 1][col] << 16);
      o.x = w4[0]; o.y = w4[1]; o.z = w4[2]; o.w = w4[3];
      const int ks = ks32 * 2 + half;
      *(uint4*)(wbuf + (size_t)NW1 * 8 +
                ((size_t)(kl * LT2 + lt) * KT2 + ks) * 512 + lane * 8) = o;
    }
  } else if (bid < 476) {  // ---- Wh (16x16 format, unchanged) ----
    const int b3i = bid - 432;
    const int ks = b3i % 11;
    const int kk = b3i / 11;
    for (int rr = 0; rr < 8; ++rr) {
      const int r = wid * 8 + rr;
      const int l = ks * 32 + r;
      if (lane < 24) {
        const int c = lane * 4;
        float4 v = make_float4(0.f, 0.f, 0.f, 0.f);
        if (l < L) v = *(const float4*)(Wh + ((size_t)kk * L + l) * O + c);
        uint2 p;
        p.x = pack2(v.x, v.y);
        p.y = pack2(v.z, v.w);
        *(uint2*)&sm[r][c] = p;
      }
    }
    __syncthreads();
    for (int nt = wid; nt < NTH; nt += 4) {
      uint4 o;
      u32 w4[4];
#pragma unroll
      for (int jj = 0; jj < 4; ++jj) {
        const u16 a = sm[q * 8 + 2 * jj][nt * 16 + rm];
        const u16 b = sm[q * 8 + 2 * jj + 1][nt * 16 + rm];
        w4[jj] = (u32)a | ((u32)b << 16);
      }
      o.x = w4[0]; o.y = w4[1]; o.z = w4[2]; o.w = w4[3];
      *(uint4*)(wbuf + (size_t)(NW1 + NW2) * 8 +
                ((size_t)(kk * NTH + nt) * KSH + ks) * 512 + lane * 8) = o;
    }
  } else {  // ---- tables ----
    __shared__ int wcnt[4][K];
    __shared__ int pre[4][K];
    __shared__ int cofs[K + 1];
    const int a = assign[tid];
    const u64 below = (1ull << lane) - 1ull;
    int myrank = 0;
#pragma unroll
    for (int k = 0; k < K; ++k) {
      const u64 m = __ballot(a == k);
      if (a == k) myrank = (int)__popcll(m & below);
      if (lane == 0) wcnt[wid][k] = (int)__popcll(m);
    }
    __syncthreads();
    if (tid == 0) {
      int tot[K];
      for (int k = 0; k < K; ++k) {
        int s = 0;
        for (int ww = 0; ww < 4; ++ww) {
          pre[ww][k] = s;
          s += wcnt[ww][k];
        }
        tot[k] = s;
      }
      cofs[0] = 0;
      for (int k = 0; k < K; ++k) cofs[k + 1] = cofs[k] + tot[k];
      for (int k = 0; k <= K; ++k) meta[512 + k] = cofs[k];
    }
    __syncthreads();
    const int pos = cofs[a] + pre[wid][a] + myrank;
    meta[256 + pos] = tid;  // chlist
    meta[520 + tid] = pos;  // ipos (inverse chlist)
    int k = 0;
    while (k < K - 1 && tid >= cofs[k + 1]) ++k;
    meta[tid] = (k << 16) | ((tid - cofs[k]) * TM);
  }
}

// ---- main kernel: 16 waves/block, 1 block/CU, 32x32x16 MFMA ----
__global__ __launch_bounds__(1024, 4) void mlp_mfma(
    const float* __restrict__ x, const float* __restrict__ rev_w,
    const float* __restrict__ rev_b, const float* __restrict__ b1,
    const float* __restrict__ b2, const float* __restrict__ bh,
    const int* __restrict__ meta, const u16* __restrict__ wbuf) {
  __shared__ __align__(16) u16 zb[TM][ZBS];  // 23.0 KB
  __shared__ __align__(16) u16 Hsh[TM][HS];  // 66.0 KB
  __shared__ float s_mean[TM], s_std[TM], s_rw[TM], s_rb[TM];
  __shared__ int s_b[TM], s_p[TM];

  const int tid = threadIdx.x;
  const int wid = tid >> 6;  // 0..15
  const int lane = tid & 63;
  const int q = lane >> 4, rm = lane & 15;    // head (16x16)
  const int q2 = lane >> 5, n32 = lane & 31;  // 32x32

  const int swz = (blockIdx.x & 7) * 32 + (blockIdx.x >> 3);
  const int info = meta[swz];
  const int kcl = info >> 16;
  const int rstart = info & 0xffff;
  const int cofs = meta[512 + kcl];
  const int cnt = meta[512 + kcl + 1] - cofs;

  // ---- RevIN: 2 rows per wave ----
  for (int i = 0; i < 2; ++i) {
    const int t = wid * 2 + i;
    const int ri = rstart + t;
    const int b = ri / cnt;
    const int c = meta[256 + cofs + (ri % cnt)];
    const float* xrow = x + (size_t)(b * C + c) * L;
    float v[6], s = 0.f, s2 = 0.f;
#pragma unroll
    for (int jj = 0; jj < 6; ++jj) {
      const int j = lane + jj * 64;
      v[jj] = (j < L) ? xrow[j] : 0.f;
      s += v[jj];
      s2 += v[jj] * v[jj];
    }
#pragma unroll
    for (int off = 32; off > 0; off >>= 1) {
      s += __shfl_down(s, off);
      s2 += __shfl_down(s2, off);
    }
    s = __shfl(s, 0);
    s2 = __shfl(s2, 0);
    const float mean = s * (1.f / L);
    const float var = s2 * (1.f / L) - mean * mean;
    const float stdv = sqrtf(var + 1e-5f);
    const float rstd = 1.f / stdv;
    const float rw = rev_w[c], rb_ = rev_b[c];
#pragma unroll
    for (int jj = 0; jj < 6; ++jj) {
      const int j = lane + jj * 64;
      if (j < L) zb[t][j] = f2bf((v[jj] - mean) * rstd * rw + rb_);
    }
    if (lane < LP - L) zb[t][L + lane] = 0;
    if (lane == 0) {
      s_mean[t] = mean;
      s_std[t] = stdv;
      s_rw[t] = rw;
      s_rb[t] = rb_;
      s_b[t] = b;
      s_p[t] = cofs + (ri % cnt);  // cluster-packed channel position
    }
  }

  const u16* w1b = wbuf;
  const u16* w2b = wbuf + (size_t)NW1 * 8;
  const u16* whb = wbuf + (size_t)(NW1 + NW2) * 8;

  // preload layer-0 phase-1 ring (2 d-tiles x depth 4) before barrier
  bf16x8 a1[2][4];
  {
    const u16* b0 = w1b + (size_t)(kcl * NL) * W1FRAGS * 8 +
                    (size_t)(wid * 2) * TS1 + lane * 8;
#pragma unroll
    for (int t = 0; t < 2; ++t)
#pragma unroll
      for (int s = 0; s < 4; ++s)
        a1[t][s] = *(const bf16x8*)(b0 + (size_t)t * TS1 + s * 512);
  }
  __syncthreads();  // zb ready

  // ---- fp32 residual master (D32 layout), waves 0..10 own l-tile wid ----
  f32x16 zm;
#pragma unroll
  for (int i = 0; i < 16; ++i) zm[i] = 0.f;
  if (wid < LT2) {
#pragma unroll
    for (int g = 0; g < 4; ++g) {
      const uint2 zw = *(const uint2*)&zb[n32][32 * wid + 8 * g + 4 * q2];
      zm[4 * g + 0] = bf2f((u16)zw.x);
      zm[4 * g + 1] = bf2f((u16)(zw.x >> 16));
      zm[4 * g + 2] = bf2f((u16)zw.y);
      zm[4 * g + 3] = bf2f((u16)(zw.y >> 16));
    }
  }

  for (int l = 0; l < NL; ++l) {
    const int kl = kcl * NL + l;
    const u16* W1f = w1b + (size_t)kl * W1FRAGS * 8;
    const u16* W2f = w2b + (size_t)kl * W2FRAGS * 8;
    const float* b1p = b1 + kl * DFF;
    const float* b2p = b2 + kl * L;
    const u16* base1 = W1f + (size_t)(wid * 2) * TS1 + lane * 8;

    // -- phase 1: H = relu(z @ W1 + b1); 2 d-tiles/wave, depth-4 ring
    f32x16 acc[2];
#pragma unroll
    for (int t = 0; t < 2; ++t)
#pragma unroll
      for (int i = 0; i < 16; ++i) acc[t][i] = 0.f;
#pragma unroll
    for (int ks = 0; ks < KT1; ++ks) {
      const bf16x8 zf = *(const bf16x8*)&zb[n32][ks * 16 + q2 * 8];
#pragma unroll
      for (int t = 0; t < 2; ++t)
        acc[t] = __builtin_amdgcn_mfma_f32_32x32x16_bf16(a1[t][ks & 3], zf,
                                                         acc[t], 0, 0, 0);
      if (ks + 4 < KT1) {
#pragma unroll
        for (int t = 0; t < 2; ++t)
          a1[t][ks & 3] =
              *(const bf16x8*)(base1 + (size_t)t * TS1 + (ks + 4) * 512);
      }
    }
    // epilogue: bias+relu, write Hsh[sample][d]
#pragma unroll
    for (int t = 0; t < 2; ++t) {
      const int dt = wid * 2 + t;
#pragma unroll
      for (int g = 0; g < 4; ++g) {
        const int db = dt * 32 + 8 * g + 4 * q2;
        const float4 bq = *(const float4*)(b1p + db);
        uint2 hw;
        hw.x = pack2(fmaxf(acc[t][4 * g + 0] + bq.x, 0.f),
                     fmaxf(acc[t][4 * g + 1] + bq.y, 0.f));
        hw.y = pack2(fmaxf(acc[t][4 * g + 2] + bq.z, 0.f),
                     fmaxf(acc[t][4 * g + 3] + bq.w, 0.f));
        *(uint2*)&Hsh[n32][db] = hw;
      }
    }

    // preload phase-2 ring (depth 8) before the barrier (global-only)
    bf16x8 a2[8];
    const u16* base2 = W2f + (size_t)wid * TS2 + lane * 8;
    if (wid < LT2) {
#pragma unroll
      for (int s = 0; s < 8; ++s)
        a2[s] = *(const bf16x8*)(base2 + s * 512);
    }
    __syncthreads();  // Hsh ready

    // -- phase 2: zm += H @ W2; 1 l-tile/wave (waves 0..10), depth-8 ring
    if (wid < LT2) {
#pragma unroll
      for (int ks = 0; ks < KT2; ++ks) {
        const bf16x8 hf = *(const bf16x8*)&Hsh[n32][ks * 16 + q2 * 8];
        zm = __builtin_amdgcn_mfma_f32_32x32x16_bf16(a2[ks & 7], hf, zm, 0, 0, 0);
        if (ks + 8 < KT2)
          a2[ks & 7] = *(const bf16x8*)(base2 + (ks + 8) * 512);
      }
      // epilogue: zm += b2, refresh bf16 zb
#pragma unroll
      for (int g = 0; g < 4; ++g) {
        const int lc = 32 * wid + 8 * g + 4 * q2;
        if (lc < L) {
          const float4 bq = *(const float4*)(b2p + lc);
          zm[4 * g + 0] += bq.x;
          zm[4 * g + 1] += bq.y;
          zm[4 * g + 2] += bq.z;
          zm[4 * g + 3] += bq.w;
        }
        uint2 zw;
        zw.x = pack2(zm[4 * g + 0], zm[4 * g + 1]);
        zw.y = pack2(zm[4 * g + 2], zm[4 * g + 3]);
        *(uint2*)&zb[n32][lc] = zw;
      }
    }

    // preload next layer's phase-1 ring before the barrier (global-only)
    if (l + 1 < NL) {
      const u16* nb = w1b + (size_t)(kl + 1) * W1FRAGS * 8 +
                      (size_t)(wid * 2) * TS1 + lane * 8;
#pragma unroll
      for (int t = 0; t < 2; ++t)
#pragma unroll
        for (int s = 0; s < 4; ++s)
          a1[t][s] = *(const bf16x8*)(nb + (size_t)t * TS1 + s * 512);
    }
    __syncthreads();  // zb final for this layer
  }

  // ---- head (16x16 path): g_y[b][o][p] = denorm(z @ Wh + bh), packed ----
  if (wid < NTH) {
    const u16* Whf =
        whb + (size_t)kcl * WHFRAGS * 8 + (size_t)wid * THS + lane * 8;
    f32x4 acc0 = {0.f, 0.f, 0.f, 0.f}, acc1 = {0.f, 0.f, 0.f, 0.f};
    for (int ks = 0; ks < KSH; ++ks) {
      const bf16x8 af = *(const bf16x8*)(Whf + ks * 512);
      const bf16x8 zf0 = *(const bf16x8*)&zb[rm][ks * 32 + q * 8];
      const bf16x8 zf1 = *(const bf16x8*)&zb[rm + 16][ks * 32 + q * 8];
      acc0 = __builtin_amdgcn_mfma_f32_16x16x32_bf16(af, zf0, acc0, 0, 0, 0);
      acc1 = __builtin_amdgcn_mfma_f32_16x16x32_bf16(af, zf1, acc1, 0, 0, 0);
    }
    const float4 bq = *(const float4*)(bh + kcl * O + wid * 16 + q * 4);
    const float bqa[4] = {bq.x, bq.y, bq.z, bq.w};
#pragma unroll
    for (int rg = 0; rg < 2; ++rg) {
      const int row = rm + 16 * rg;
      const float mean = s_mean[row], stdv = s_std[row];
      const float rw = s_rw[row], rb_ = s_rb[row];
      const int ob = s_b[row], pp = s_p[row];
      const f32x4 acc = rg ? acc1 : acc0;
#pragma unroll
      for (int gg = 0; gg < 4; ++gg) {
        const int o = wid * 16 + q * 4 + gg;
        const float v = acc[gg] + bqa[gg];
        // packed-channel layout: consecutive rows (rm) -> consecutive pp
        // -> full-line, single-writer 64B stores
        g_y[((size_t)ob * O + o) * C + pp] = (v - rb_) / rw * stdv + mean;
      }
    }
  }
}

// ---- permute g_y (cluster-packed channels) -> out[b][o][c] ----
// writes fully coalesced; reads gather within a 1KB window (L1/L2-hit)
__global__ __launch_bounds__(1024) void scatter_out(
    const int* __restrict__ meta, float* __restrict__ out) {
  const int row = blockIdx.x * 4 + (threadIdx.x >> 8);  // (b*O+o)
  const int c = threadIdx.x & 255;
  const int p = meta[520 + c];  // packed position of channel c
  out[(size_t)row * C + c] = g_y[(size_t)row * C + p];
}

extern "C" void kernel_launch(void* const* d_in, const int* in_sizes, int n_in,
                              void* d_out, int out_size, void* d_ws,
                              size_t ws_size, hipStream_t stream) {
  const float* x = (const float*)d_in[0];
  const float* rev_w = (const float*)d_in[1];
  const float* rev_b = (const float*)d_in[2];
  const float* W1 = (const float*)d_in[3];
  const float* b1 = (const float*)d_in[4];
  const float* W2 = (const float*)d_in[5];
  const float* b2 = (const float*)d_in[6];
  const float* Wh = (const float*)d_in[7];
  const float* bh = (const float*)d_in[8];
  const int* assign = (const int*)d_in[9];
  float* out = (float*)d_out;

  int* meta = (int*)d_ws;                  // ~3.1 KB
  u16* wbuf = (u16*)((char*)d_ws + 4096);  // 11.6 MB bf16 fragments

  prep<<<NPREP, 256, 0, stream>>>(assign, W1, W2, Wh, meta, wbuf);
  mlp_mfma<<<NTILES, 1024, 0, stream>>>(x, rev_w, rev_b, b1, b2, bh, meta,
                                        wbuf);
  scatter_out<<<(B * O) / 4, 1024, 0, stream>>>(meta, out);
}